// Round 1
// baseline (276.264 us; speedup 1.0000x reference)
//
#include <hip/hip_runtime.h>

// MySoftBCELoss: per-row l = argmax(target); loss = -mean(t[l]*log(p[l]) + log(1-p[0]))
// where p = clamp(sigmoid(logits), 1e-7, 1-1e-7).
// B=524288 rows, C=64 cols (f32). Memory-bound: 268.4 MB read -> ~43 us floor @ 6.3 TB/s.

#define GRID 2048
#define BLOCK 256

constexpr int   C_   = 64;
constexpr int   B_   = 524288;
constexpr float EPS_ = 1e-7f;

__global__ __launch_bounds__(BLOCK) void softbce_partial(
    const float* __restrict__ logits,
    const float* __restrict__ target,
    float* __restrict__ partials)
{
    const int lane   = threadIdx.x & 63;   // lane in wave
    const int g      = lane & 15;          // lane in 16-lane row-group
    const int waveId = threadIdx.x >> 6;   // 0..3
    const int subrow = lane >> 4;          // 0..3 (row within wave)

    float acc = 0.0f;

    const int totalChunks = B_ / 16;       // 16 rows per block-iteration
    for (int chunk = blockIdx.x; chunk < totalChunks; chunk += GRID) {
        const int row  = chunk * 16 + waveId * 4 + subrow;
        const int base = row * C_ + g * 4;

        const float4 t4 = *(const float4*)(target + base);
        const float4 x4 = *(const float4*)(logits + base);

        // local argmax over this lane's 4 target values (first-occurrence on ties)
        float bv = t4.x; int bi = g * 4;
        if (t4.y > bv) { bv = t4.y; bi = g * 4 + 1; }
        if (t4.z > bv) { bv = t4.z; bi = g * 4 + 2; }
        if (t4.w > bv) { bv = t4.w; bi = g * 4 + 3; }

        // 16-lane butterfly argmax, lowest-index tie-break (matches jnp.argmax)
        #pragma unroll
        for (int off = 8; off; off >>= 1) {
            float ov = __shfl_xor(bv, off, 16);
            int   oi = __shfl_xor(bi, off, 16);
            if (ov > bv || (ov == bv && oi < bi)) { bv = ov; bi = oi; }
        }
        // bi = label (uniform in group), bv = target[row, label]

        const int e = bi & 3;
        const float xsel = (e == 0) ? x4.x : (e == 1) ? x4.y : (e == 2) ? x4.z : x4.w;
        const float x_l = __shfl(xsel, bi >> 2, 16);  // logits[row, label] from owner lane
        const float x_0 = __shfl(x4.x, 0, 16);        // logits[row, 0]

        if (g == 0) {
            const float p_l = fminf(fmaxf(1.0f / (1.0f + __expf(-x_l)), EPS_), 1.0f - EPS_);
            const float p_0 = fminf(fmaxf(1.0f / (1.0f + __expf(-x_0)), EPS_), 1.0f - EPS_);
            acc += bv * __logf(p_l) + __logf(1.0f - p_0);
        }
    }

    // block reduction: wave butterfly (non-g0 lanes hold 0), then LDS across 4 waves
    #pragma unroll
    for (int off = 32; off; off >>= 1) acc += __shfl_xor(acc, off, 64);

    __shared__ float s[4];
    if (lane == 0) s[waveId] = acc;
    __syncthreads();
    if (threadIdx.x == 0) partials[blockIdx.x] = s[0] + s[1] + s[2] + s[3];
}

__global__ __launch_bounds__(256) void softbce_final(
    const float* __restrict__ partials, float* __restrict__ out)
{
    float acc = 0.0f;
    for (int i = threadIdx.x; i < GRID; i += 256) acc += partials[i];

    #pragma unroll
    for (int off = 32; off; off >>= 1) acc += __shfl_xor(acc, off, 64);

    __shared__ float s[4];
    const int waveId = threadIdx.x >> 6;
    if ((threadIdx.x & 63) == 0) s[waveId] = acc;
    __syncthreads();
    if (threadIdx.x == 0) out[0] = -(s[0] + s[1] + s[2] + s[3]) / (float)B_;
}

extern "C" void kernel_launch(void* const* d_in, const int* in_sizes, int n_in,
                              void* d_out, int out_size, void* d_ws, size_t ws_size,
                              hipStream_t stream) {
    const float* logits = (const float*)d_in[0];
    const float* target = (const float*)d_in[1];
    float* out      = (float*)d_out;
    float* partials = (float*)d_ws;   // GRID floats = 8 KB scratch

    softbce_partial<<<GRID, BLOCK, 0, stream>>>(logits, target, partials);
    softbce_final<<<1, 256, 0, stream>>>(partials, out);
}

// Round 2
// 276.170 us; speedup vs baseline: 1.0003x; 1.0003x over previous
//
#include <hip/hip_runtime.h>

// MySoftBCELoss: per-row l = argmax(target); loss = -mean(t[l]*log(p[l]) + log(1-p[0]))
// where p = clamp(sigmoid(logits), 1e-7, 1-1e-7).
// B=524288 rows, C=64 cols (f32). 268 MB read -> ~43 us HBM floor (less w/ L3 hits).
//
// R1 -> R2: latency-bound fix. (a) owner-lane-computes pattern removes the two
// dynamic ds_bpermute broadcasts; (b) 4x chunk unroll gives 8 loads + 4
// independent butterfly chains in flight per wave.

#define GRID 2048
#define BLOCK 256
#define UNROLL 4

constexpr int   C_   = 64;
constexpr int   B_   = 524288;
constexpr float EPS_ = 1e-7f;

__global__ __launch_bounds__(BLOCK) void softbce_partial(
    const float* __restrict__ logits,
    const float* __restrict__ target,
    float* __restrict__ partials)
{
    const int lane   = threadIdx.x & 63;   // lane in wave
    const int g      = lane & 15;          // lane in 16-lane row-group
    const int waveId = threadIdx.x >> 6;   // 0..3
    const int subrow = lane >> 4;          // 0..3 (row within wave)

    float acc = 0.0f;

    const int totalChunks = B_ / 16;             // 32768; 16 rows per block-chunk
    // 32768 / (GRID*UNROLL) = 4 outer iterations, exact.
    for (int c0 = blockIdx.x * UNROLL; c0 < totalChunks; c0 += GRID * UNROLL) {
        float4 t4[UNROLL], x4[UNROLL];

        #pragma unroll
        for (int u = 0; u < UNROLL; ++u) {
            const int row  = (c0 + u) * 16 + waveId * 4 + subrow;
            const int base = row * C_ + g * 4;
            t4[u] = *(const float4*)(target + base);
            x4[u] = *(const float4*)(logits + base);
        }

        #pragma unroll
        for (int u = 0; u < UNROLL; ++u) {
            // local argmax over this lane's 4 target values (first-occurrence on ties)
            float bv = t4[u].x; int bi = g * 4;
            if (t4[u].y > bv) { bv = t4[u].y; bi = g * 4 + 1; }
            if (t4[u].z > bv) { bv = t4[u].z; bi = g * 4 + 2; }
            if (t4[u].w > bv) { bv = t4[u].w; bi = g * 4 + 3; }

            // 16-lane butterfly argmax, lowest-index tie-break (matches jnp.argmax)
            #pragma unroll
            for (int off = 8; off; off >>= 1) {
                float ov = __shfl_xor(bv, off, 16);
                int   oi = __shfl_xor(bi, off, 16);
                if (ov > bv || (ov == bv && oi < bi)) { bv = ov; bi = oi; }
            }
            // every lane in the group now has (bv=t_max, bi=label); no broadcasts:
            // owner lane computes the label term from its own registers.
            if ((bi >> 2) == g) {
                const int e = bi & 3;
                const float x_l = (e == 0) ? x4[u].x : (e == 1) ? x4[u].y
                                 : (e == 2) ? x4[u].z : x4[u].w;
                const float p_l = fminf(fmaxf(1.0f / (1.0f + __expf(-x_l)), EPS_), 1.0f - EPS_);
                acc += bv * __logf(p_l);
            }
            // lane 0 of the group owns logits[row, 0].
            if (g == 0) {
                const float p_0 = fminf(fmaxf(1.0f / (1.0f + __expf(-x4[u].x)), EPS_), 1.0f - EPS_);
                acc += __logf(1.0f - p_0);
            }
        }
    }

    // block reduction: wave butterfly, then LDS across 4 waves
    #pragma unroll
    for (int off = 32; off; off >>= 1) acc += __shfl_xor(acc, off, 64);

    __shared__ float s[4];
    if (lane == 0) s[waveId] = acc;
    __syncthreads();
    if (threadIdx.x == 0) partials[blockIdx.x] = s[0] + s[1] + s[2] + s[3];
}

__global__ __launch_bounds__(256) void softbce_final(
    const float* __restrict__ partials, float* __restrict__ out)
{
    float acc = 0.0f;
    for (int i = threadIdx.x; i < GRID; i += 256) acc += partials[i];

    #pragma unroll
    for (int off = 32; off; off >>= 1) acc += __shfl_xor(acc, off, 64);

    __shared__ float s[4];
    const int waveId = threadIdx.x >> 6;
    if ((threadIdx.x & 63) == 0) s[waveId] = acc;
    __syncthreads();
    if (threadIdx.x == 0) out[0] = -(s[0] + s[1] + s[2] + s[3]) / (float)B_;
}

extern "C" void kernel_launch(void* const* d_in, const int* in_sizes, int n_in,
                              void* d_out, int out_size, void* d_ws, size_t ws_size,
                              hipStream_t stream) {
    const float* logits = (const float*)d_in[0];
    const float* target = (const float*)d_in[1];
    float* out      = (float*)d_out;
    float* partials = (float*)d_ws;   // GRID floats = 8 KB scratch

    softbce_partial<<<GRID, BLOCK, 0, stream>>>(logits, target, partials);
    softbce_final<<<1, 256, 0, stream>>>(partials, out);
}